// Round 5
// baseline (335.071 us; speedup 1.0000x reference)
//
#include <hip/hip_runtime.h>
#include <stdint.h>

#define BB   8192
#define DD   1024
#define EE   8
#define RHH  128
#define EHH  256
#define NE1  2048        // E*EH
#define KX   2112        // NE1 + 64 (8 bias cols + 56 zero pad), %64==0

using f32x4  = __attribute__((ext_vector_type(4))) float;
using bf16x8 = __attribute__((ext_vector_type(8))) __bf16;

__device__ __forceinline__ unsigned short f2bf(float f) {
    union { float f; uint32_t u; } v; v.f = f;
    uint32_t u = v.u;
    uint32_t r = (u + 0x7FFFu + ((u >> 16) & 1u)) >> 16;
    return (unsigned short)r;
}
__device__ __forceinline__ float bf2f(unsigned short h) {
    union { uint32_t u; float f; } v; v.u = ((uint32_t)h) << 16;
    return v.f;
}

__device__ __forceinline__ void llds16(void* l, const void* g) {
    __builtin_amdgcn_global_load_lds(
        (const __attribute__((address_space(1))) uint32_t*)g,
        (__attribute__((address_space(3))) uint32_t*)l, 16, 0, 0);
}

__device__ __forceinline__ void rawbar() {
    asm volatile("" ::: "memory");
    __builtin_amdgcn_s_barrier();
    asm volatile("" ::: "memory");
}

template<int N> __device__ __forceinline__ void vmwait() {
    asm volatile("s_waitcnt vmcnt(%0)" :: "n"(N) : "memory");
}

__device__ __forceinline__ void lgkm0sb() {
    asm volatile("s_waitcnt lgkmcnt(0)" ::: "memory");
    __builtin_amdgcn_sched_barrier(0);
}

#define MFMA16(a,b,c) __builtin_amdgcn_mfma_f32_16x16x32_bf16(a,b,c,0,0,0)

// ---------------- prep bodies ----------------

__device__ __forceinline__ void prep_body(int pbid, int tid,
    const float* __restrict__ rw1, const float* __restrict__ ew1,
    const float* __restrict__ ew2, const float* __restrict__ eb2,
    unsigned short* __restrict__ rw1t, unsigned short* __restrict__ W1t,
    unsigned short* __restrict__ W2t)
{
    if (pbid < 512) {                       // rw1t[h][d] = rw1[d][h]  (128x1024)
        int o = pbid * 256 + tid;
        int h = o >> 10, d = o & 1023;
        rw1t[o] = f2bf(rw1[d * RHH + h]);
    } else if (pbid < 8704) {               // W1t[n][k] = ew1[e][k][h], n=e*256+h
        int o = (pbid - 512) * 256 + tid;
        int n = o >> 10, k = o & 1023;
        int e = n >> 8, hh = n & 255;
        W1t[o] = f2bf(ew1[((e << 10) + k) * 256 + hh]);
    } else {                                // W2t[d][np] with bias rows + zero pad
        int o = (pbid - 8704) * 256 + tid;  // up to 1024*2112
        int d = o / KX;
        int np = o - d * KX;
        float v;
        if (np < NE1)            v = ew2[np * DD + d];
        else if (np < NE1 + EE)  v = eb2[(np - NE1) * DD + d];
        else                     v = 0.0f;
        W2t[o] = f2bf(v);
    }
}

// mega0: x->bf16 cvt (blocks [0,2048)), Hb zero-pads (blocks [2048,3840)),
//        level-0 prep (blocks [3840,20992))
__global__ __launch_bounds__(256) void mega0(
    const float* __restrict__ x, unsigned short* __restrict__ xb,
    unsigned short* __restrict__ Hb,
    const float* __restrict__ rw1, const float* __restrict__ ew1,
    const float* __restrict__ ew2, const float* __restrict__ eb2,
    unsigned short* __restrict__ rw1t, unsigned short* __restrict__ W1t,
    unsigned short* __restrict__ W2t)
{
    const int bid = blockIdx.x, tid = threadIdx.x;
    if (bid < 2048) {
        size_t idx = (size_t)bid * 256 + tid;      // 524288 threads * 16 elems
        const float* p = x + idx * 16;
        uint32_t w[8];
#pragma unroll
        for (int j = 0; j < 8; ++j)
            w[j] = (uint32_t)f2bf(p[2 * j]) | ((uint32_t)f2bf(p[2 * j + 1]) << 16);
        uint32_t* o = (uint32_t*)(xb + idx * 16);
        *(uint4*)(o)     = make_uint4(w[0], w[1], w[2], w[3]);
        *(uint4*)(o + 4) = make_uint4(w[4], w[5], w[6], w[7]);
    } else if (bid < 3840) {
        int idx = (bid - 2048) * 256 + tid;        // 8192*56
        int row = idx / 56, j = idx - row * 56;
        Hb[(size_t)row * KX + NE1 + EE + j] = 0;
    } else {
        prep_body(bid - 3840, tid, rw1, ew1, ew2, eb2, rw1t, W1t, W2t);
    }
}

__global__ __launch_bounds__(256) void prep_all(
    const float* __restrict__ rw1, const float* __restrict__ ew1,
    const float* __restrict__ ew2, const float* __restrict__ eb2,
    unsigned short* __restrict__ rw1t, unsigned short* __restrict__ W1t,
    unsigned short* __restrict__ W2t)
{
    prep_body(blockIdx.x, threadIdx.x, rw1, ew1, ew2, eb2, rw1t, W1t, W2t);
}

// ---------------- fused router (unchanged from round 4) ----------------
__global__ __launch_bounds__(512, 2) void router_fused(
    const unsigned short* __restrict__ xb, const unsigned short* __restrict__ rw1t,
    const float* __restrict__ rw2, const float* __restrict__ rb1,
    const float* __restrict__ rb2, float* __restrict__ wbuf,
    unsigned short* __restrict__ Hb)
{
    __shared__ __align__(16) char SR[73728];   // 3 bufs x (xs 8KB + ws 16KB); tail: rhs+lg

    const int tid = threadIdx.x;
    const int lane = tid & 63, wv = tid >> 6;
    const int g = wv >> 2, wq = wv & 3;
    const int l16 = lane & 15, lhi = lane >> 4;
    const long m0 = (long)blockIdx.x * 64;

    const int r0 = tid >> 2, sl = tid & 3;
    const int sg = sl ^ ((r0 >> 1) & 3);

    const int xrow = (tid >> 2) & 63, xkg = tid >> 8;
    const char* xsrc = (const char*)xb + (m0 + xrow) * 2048 + xkg * 1024 + sg * 16;
    const char* wsrc = (const char*)rw1t + (long)r0 * 2048 + sg * 16;

    f32x4 acc[8];
    const f32x4 zero = {0.f, 0.f, 0.f, 0.f};
#pragma unroll
    for (int i = 0; i < 8; ++i) acc[i] = zero;

    auto stage = [&](int buf, int t) {
        char* base = SR + buf * 24576;
        llds16(base + tid * 16, xsrc + t * 64);
        llds16(base + 8192 + tid * 16, wsrc + t * 64);
        llds16(base + 16384 + tid * 16, wsrc + 1024 + t * 64);
    };

    stage(0, 0); stage(1, 1);

    const int swz = (l16 >> 1) & 3;
    const int aoff = g * 2048 + (wq * 16 + l16) * 32 + ((lhi ^ swz) << 3);
    const int boff = 4096 + g * 4096 + l16 * 32 + ((lhi ^ swz) << 3);

    int cb = 0, sb = 2;
    for (int t = 0; t < 16; ++t) {
        if (t < 15) vmwait<3>(); else vmwait<0>();
        rawbar();
        const unsigned short* bufp = (const unsigned short*)(SR + cb * 24576);
        bf16x8 aF = *(const bf16x8*)&bufp[aoff];
        bf16x8 bF[8];
#pragma unroll
        for (int ni = 0; ni < 8; ++ni)
            bF[ni] = *(const bf16x8*)&bufp[boff + ni * 512];
        if (t + 2 < 16) stage(sb, t + 2);
        __builtin_amdgcn_s_setprio(1);
#pragma unroll
        for (int ni = 0; ni < 8; ++ni)
            acc[ni] = MFMA16(aF, bF[ni], acc[ni]);
        __builtin_amdgcn_s_setprio(0);
        cb = (cb + 1 == 3) ? 0 : cb + 1;
        sb = (sb + 1 == 3) ? 0 : sb + 1;
    }

    rawbar();

    float* rhs = (float*)SR;                     // [64][132]
    float* lg  = (float*)(SR + 64 * 132 * 4);    // [64][9]

    if (g == 1) {
#pragma unroll
        for (int ni = 0; ni < 8; ++ni)
#pragma unroll
            for (int rr = 0; rr < 4; ++rr)
                rhs[(wq * 16 + lhi * 4 + rr) * 132 + ni * 16 + l16] = acc[ni][rr];
    }
    rawbar();
    if (g == 0) {
#pragma unroll
        for (int ni = 0; ni < 8; ++ni) {
            float bv = rb1[ni * 16 + l16];
#pragma unroll
            for (int rr = 0; rr < 4; ++rr) {
                int row = wq * 16 + lhi * 4 + rr, col = ni * 16 + l16;
                float v = acc[ni][rr] + rhs[row * 132 + col] + bv;
                rhs[row * 132 + col] = fmaxf(v, 0.f);
            }
        }
    }
    rawbar();

    {
        const int row = tid & 63, e = tid >> 6;
        float a2 = rb2[e];
        for (int h = 0; h < 128; ++h)
            a2 += rhs[row * 132 + h] * rw2[h * 8 + e];
        lg[row * 9 + e] = a2;
    }
    rawbar();

    if (tid < 64) {
        const int row = tid;
        float l[8], m = -1e30f;
#pragma unroll
        for (int e = 0; e < 8; ++e) { l[e] = lg[row * 9 + e]; m = fmaxf(m, l[e]); }
        float s = 0.f;
#pragma unroll
        for (int e = 0; e < 8; ++e) { l[e] = expf(l[e] - m); s += l[e]; }
        float inv = 1.f / s;
        const long gr = m0 + row;
#pragma unroll
        for (int e = 0; e < 8; ++e) {
            float w = l[e] * inv;
            wbuf[gr * 8 + e] = w;
            Hb[gr * KX + NE1 + e] = f2bf(w);
        }
    }
}

// ---------------- fine-phase (m201-style) 256xBN GEMM ----------------
// C[M,N] = A[M,K]*Bt[N,K]^T. BM=256, BK=64 (2 kh of 32), 512 thr = 8 waves (2M x 4N),
// per-wave 128 x (BNv/4). 2 full-tile LDS buffers (parity). Phase = {ds_read subtile;
// stage 1 unit (2 gload_lds); barrier; lgkmcnt(0); setprio(1); 16 MFMA; setprio(0);
// barrier}. 4 phases/tile (BNv=256, quadrants (mih,nih)) or 2 (BNv=128, mih halves).
// Stage schedule (BNv=256): tP0:Bn0(t+1) tP1:Bn1(t+1) tP2:Am0(t+2) tP3:Am1(t+2);
// A(t+2) overwrites current buffer's mih-region AFTER its last reader phase (>=1 barrier).
// Boundary wait once per tile: vmcnt(4) [BNv=128: vmcnt(2)], tail vmcnt(0) at t=nt-1.
// EPI 1: bf16(relu(acc+bias[n])*wrow[m][n>>8]); EPI 2: bf16(acc); EPI 3: f32(acc)
template<int BNv, int EPI>
__global__ __launch_bounds__(512, 2)
void gemmF(const unsigned short* __restrict__ A, const unsigned short* __restrict__ Bt,
           void* __restrict__ C, const float* __restrict__ bias,
           const float* __restrict__ wrow,
           int K, int lda, int ldb, int ldc)
{
    constexpr int NC  = BNv / 4;           // 64 or 32
    constexpr int NI  = NC / 16;           // 4 or 2
    constexpr int BKH = BNv * 32;          // ushorts per B kh-region

    __shared__ __align__(16) unsigned short As[2][16384];
    __shared__ __align__(16) unsigned short Bs[2][2 * BKH];

    const int tid = threadIdx.x;
    const int lane = tid & 63, wv = tid >> 6;
    const int wr = wv >> 2, wc = wv & 3;
    const int l16 = lane & 15, lhi = lane >> 4;
    const int lq = lane >> 2, ls = lane & 3;

    const long bm0 = (long)blockIdx.x * 256;
    const long bn0 = (long)blockIdx.y * BNv;

    // staging geometry: chunk = 16 rows x one kh; wave -> row group, gload g -> kh
    const int arb = (wv & 3) * 16 + (wv >> 2) * 128 + lq;   // A unit-relative row
    const int sgA = ls ^ ((arb >> 1) & 3);
    const int brb = (BNv == 256) ? ((wv >> 1) * 64 + (wv & 1) * 16 + lq)
                                 : (wv * 16 + lq);
    const int sgB = ls ^ ((brb >> 1) & 3);

    const char* aSrcU[2];
    aSrcU[0] = (const char*)A + (bm0 + arb) * (long)lda * 2 + sgA * 16;
    aSrcU[1] = aSrcU[0] + 64 * (long)lda * 2;
    const char* bSrcU[2];
    bSrcU[0] = (const char*)Bt + (bn0 + brb) * (long)ldb * 2 + sgB * 16;
    bSrcU[1] = bSrcU[0] + 32 * (long)ldb * 2;   // only BNv==256 uses [1]

    const int aDst0 = arb * 64 + ls * 16;        // byte offset within buffer (g=0)
    const int bDst0 = brb * 64 + ls * 16;

    auto stA = [&](int buf, int mih, int t) {    // one A unit: 2 gloads (kh0,kh1)
#pragma unroll
        for (int g = 0; g < 2; ++g)
            llds16((char*)As + buf * 32768 + g * 16384 + aDst0 + mih * 4096,
                   aSrcU[mih] + (long)t * 128 + g * 64);
    };
    auto stB = [&](int buf, int nih, int t) {    // one B unit: 2 gloads
#pragma unroll
        for (int g = 0; g < 2; ++g)
            llds16((char*)Bs + buf * (4 * BKH) + g * (2 * BKH) + bDst0 + nih * 2048,
                   bSrcU[nih] + (long)t * 128 + g * 64);
    };

    f32x4 acc[8][NI];
    const f32x4 zero = {0.f, 0.f, 0.f, 0.f};
#pragma unroll
    for (int i = 0; i < 8; ++i)
#pragma unroll
        for (int j = 0; j < NI; ++j)
            acc[i][j] = zero;

    const int swzo = (lhi ^ ((l16 >> 1) & 3)) << 3;
    const int arow0 = (wr * 128 + l16) * 32 + swzo;   // + mih*2048 + mi*512 + kk*8192
    const int brow0 = (wc * NC + l16) * 32 + swzo;    // + ni*512 + kk*BKH

    const int nt = K / 64;

    // prologue: [A(0) units, B(0) units, A(1) units] (BNv=256)
    //           [B(0), A(0) units, B(1)]             (BNv=128)
    if constexpr (BNv == 256) {
        stA(0, 0, 0); stA(0, 1, 0);
        stB(0, 0, 0); stB(0, 1, 0);
        stA(1, 0, 1); stA(1, 1, 1);
    } else {
        stB(0, 0, 0);
        stA(0, 0, 0); stA(0, 1, 0);
        stB(1, 0, 1);
    }

    bf16x8 aF[2][4], bF[2][NI];

    for (int t = 0; t < nt; ++t) {
        const int buf = t & 1;

        if constexpr (BNv == 256) {
            // ---- P0: quadrant (mih0, nih0) ----
            if (t == nt - 1) vmwait<0>(); else vmwait<4>();
            rawbar();
#pragma unroll
            for (int kk = 0; kk < 2; ++kk)
#pragma unroll
                for (int mi = 0; mi < 4; ++mi)
                    aF[kk][mi] = *(const bf16x8*)&As[buf][kk * 8192 + arow0 + mi * 512];
#pragma unroll
            for (int kk = 0; kk < 2; ++kk)
#pragma unroll
                for (int nj = 0; nj < 2; ++nj)
                    bF[kk][nj] = *(const bf16x8*)&Bs[buf][kk * BKH + brow0 + nj * 512];
            if (t + 1 < nt) stB(buf ^ 1, 0, t + 1);
            lgkm0sb();
            __builtin_amdgcn_s_setprio(1);
#pragma unroll
            for (int kk = 0; kk < 2; ++kk)
#pragma unroll
                for (int mi = 0; mi < 4; ++mi)
#pragma unroll
                    for (int nj = 0; nj < 2; ++nj)
                        acc[mi][nj] = MFMA16(aF[kk][mi], bF[kk][nj], acc[mi][nj]);
            __builtin_amdgcn_s_setprio(0);
            rawbar();

            // ---- P1: (mih0, nih1) ----
#pragma unroll
            for (int kk = 0; kk < 2; ++kk)
#pragma unroll
                for (int nj = 0; nj < 2; ++nj)
                    bF[kk][2 + nj] = *(const bf16x8*)&Bs[buf][kk * BKH + brow0 + (2 + nj) * 512];
            if (t + 1 < nt) stB(buf ^ 1, 1, t + 1);
            rawbar();
            lgkm0sb();
            __builtin_amdgcn_s_setprio(1);
#pragma unroll
            for (int kk = 0; kk < 2; ++kk)
#pragma unroll
                for (int mi = 0; mi < 4; ++mi)
#pragma unroll
                    for (int nj = 0; nj < 2; ++nj)
                        acc[mi][2 + nj] = MFMA16(aF[kk][mi], bF[kk][2 + nj], acc[mi][2 + nj]);
            __builtin_amdgcn_s_setprio(0);
            rawbar();

            // ---- P2: (mih1, nih0) ----
#pragma unroll
            for (int kk = 0; kk < 2; ++kk)
#pragma unroll
                for (int mi = 0; mi < 4; ++mi)
                    aF[kk][mi] = *(const bf16x8*)&As[buf][kk * 8192 + arow0 + 2048 + mi * 512];
            if (t + 2 < nt) stA(buf, 0, t + 2);
            rawbar();
            lgkm0sb();
            __builtin_amdgcn_s_setprio(1);
#pragma unroll
            for (int kk = 0; kk < 2; ++kk)
#pragma unroll
                for (int mi = 0; mi < 4; ++mi)
#pragma unroll
                    for (int nj = 0; nj < 2; ++nj)
                        acc[4 + mi][nj] = MFMA16(aF[kk][mi], bF[kk][nj], acc[4 + mi][nj]);
            __builtin_amdgcn_s_setprio(0);
            rawbar();

            // ---- P3: (mih1, nih1) ----
            if (t + 2 < nt) stA(buf, 1, t + 2);
            rawbar();
            lgkm0sb();
            __builtin_amdgcn_s_setprio(1);
#pragma unroll
            for (int kk = 0; kk < 2; ++kk)
#pragma unroll
                for (int mi = 0; mi < 4; ++mi)
#pragma unroll
                    for (int nj = 0; nj < 2; ++nj)
                        acc[4 + mi][2 + nj] = MFMA16(aF[kk][mi], bF[kk][2 + nj], acc[4 + mi][2 + nj]);
            __builtin_amdgcn_s_setprio(0);
            rawbar();
        } else {
            // ---- P0: mih0, all ni ----
            if (t == nt - 1) vmwait<0>(); else vmwait<2>();
            rawbar();
#pragma unroll
            for (int kk = 0; kk < 2; ++kk)
#pragma unroll
                for (int mi = 0; mi < 4; ++mi)
                    aF[kk][mi] = *(const bf16x8*)&As[buf][kk * 8192 + arow0 + mi * 512];
#pragma unroll
            for (int kk = 0; kk < 2; ++kk)
#pragma unroll
                for (int nj = 0; nj < 2; ++nj)
                    bF[kk][nj] = *(const bf16x8*)&Bs[buf][kk * BKH + brow0 + nj * 512];
            if (t + 1 < nt) { stA(buf ^ 1, 0, t + 1); stA(buf ^ 1, 1, t + 1); }
            lgkm0sb();
            __builtin_amdgcn_s_setprio(1);
#pragma unroll
            for (int kk = 0; kk < 2; ++kk)
#pragma unroll
                for (int mi = 0; mi < 4; ++mi)
#pragma unroll
                    for (int nj = 0; nj < 2; ++nj)
                        acc[mi][nj] = MFMA16(aF[kk][mi], bF[kk][nj], acc[mi][nj]);
            __builtin_amdgcn_s_setprio(0);
            rawbar();

            // ---- P1: mih1, all ni ----
#pragma unroll
            for (int kk = 0; kk < 2; ++kk)
#pragma unroll
                for (int mi = 0; mi < 4; ++mi)
                    aF[kk][mi] = *(const bf16x8*)&As[buf][kk * 8192 + arow0 + 2048 + mi * 512];
            if (t + 2 < nt) stB(buf, 0, t + 2);
            rawbar();
            lgkm0sb();
            __builtin_amdgcn_s_setprio(1);
#pragma unroll
            for (int kk = 0; kk < 2; ++kk)
#pragma unroll
                for (int mi = 0; mi < 4; ++mi)
#pragma unroll
                    for (int nj = 0; nj < 2; ++nj)
                        acc[4 + mi][nj] = MFMA16(aF[kk][mi], bF[kk][nj], acc[4 + mi][nj]);
            __builtin_amdgcn_s_setprio(0);
            rawbar();
        }
    }

    // epilogue
#pragma unroll
    for (int mi = 0; mi < 8; ++mi) {
#pragma unroll
        for (int ni = 0; ni < NI; ++ni) {
            const long gn = bn0 + wc * NC + ni * 16 + l16;
            float bv = 0.f;
            if (EPI == 1) bv = bias[gn];
#pragma unroll
            for (int rr = 0; rr < 4; ++rr) {
                const long gm = bm0 + wr * 128 + mi * 16 + lhi * 4 + rr;
                float v = acc[mi][ni][rr];
                if (EPI == 1) {
                    v = fmaxf(v + bv, 0.f) * wrow[gm * 8 + (int)(gn >> 8)];
                    ((unsigned short*)C)[gm * (long)ldc + gn] = f2bf(v);
                } else if (EPI == 2) {
                    ((unsigned short*)C)[gm * (long)ldc + gn] = f2bf(v);
                } else {
                    ((float*)C)[gm * (long)ldc + gn] = v;
                }
            }
        }
    }
}

// ---------------- launch ----------------

extern "C" void kernel_launch(void* const* d_in, const int* in_sizes, int n_in,
                              void* d_out, int out_size, void* d_ws, size_t ws_size,
                              hipStream_t stream) {
    (void)in_sizes; (void)n_in; (void)out_size; (void)ws_size;
    const float* x   = (const float*)d_in[0];
    const float* rw1 = (const float*)d_in[1];
    const float* rb1 = (const float*)d_in[2];
    const float* rw2 = (const float*)d_in[3];
    const float* rb2 = (const float*)d_in[4];
    const float* ew1 = (const float*)d_in[5];
    const float* eb1 = (const float*)d_in[6];
    const float* ew2 = (const float*)d_in[7];
    const float* eb2 = (const float*)d_in[8];

    char* ws = (char*)d_ws;
    unsigned short* xb   = (unsigned short*)(ws);                 // 16,777,216 B
    float*          wbuf = (float*)         (ws + 16777216);      //    262,144 B
    unsigned short* Hb   = (unsigned short*)(ws + 17039360);      // 34,603,008 B
    unsigned short* rw1t = (unsigned short*)(ws + 51642368);      //    262,144 B
    unsigned short* W1t  = (unsigned short*)(ws + 51904512);      //  4,194,304 B
    unsigned short* W2t  = (unsigned short*)(ws + 56098816);      //  4,325,376 B
    // total 60,424,192 B

    mega0<<<20992, 256, 0, stream>>>(x, xb, Hb, rw1, ew1, ew2, eb2, rw1t, W1t, W2t);

    for (int l = 0; l < 3; ++l) {
        if (l > 0)
            prep_all<<<17152, 256, 0, stream>>>(rw1 + (size_t)l * DD * RHH,
                                                ew1 + (size_t)l * EE * DD * EHH,
                                                ew2 + (size_t)l * EE * EHH * DD,
                                                eb2 + (size_t)l * EE * DD,
                                                rw1t, W1t, W2t);

        router_fused<<<128, 512, 0, stream>>>(xb, rw1t,
                                              rw2 + (size_t)l * RHH * EE,
                                              rb1 + (size_t)l * RHH,
                                              rb2 + (size_t)l * EE, wbuf, Hb);

        // H' = relu(x @ W1 + b1) * w   [8192, 2048] (stride KX)
        gemmF<256, 1><<<dim3(32, 8), 512, 0, stream>>>(
            xb, W1t, Hb, eb1 + (size_t)l * NE1, wbuf, DD, DD, DD, KX);

        // out = H' @ W2ext (bias folded via K-extension)
        if (l < 2)
            gemmF<128, 2><<<dim3(32, 8), 512, 0, stream>>>(
                Hb, W2t, xb, nullptr, nullptr, KX, KX, KX, DD);
        else
            gemmF<128, 3><<<dim3(32, 8), 512, 0, stream>>>(
                Hb, W2t, d_out, nullptr, nullptr, KX, KX, KX, DD);
    }
}